// Round 9
// baseline (471.971 us; speedup 1.0000x reference)
//
#include <hip/hip_runtime.h>

#define NNODES 50000
#define NEDGES 500000
#define DIN 128
#define DHID 256
#define MPAD 50048   // padded row buffer (>= 1564*32 = 50048)
#define NI4 12500
#define NSB 49
#define GRID 782     // tiles = bid and bid+GRID; 2*GRID = 1564 tiles cover 50048 rows

typedef unsigned short u16;
typedef __attribute__((ext_vector_type(8))) _Float16 half8;
typedef __attribute__((ext_vector_type(4))) float f32x4;

__device__ __forceinline__ u16 f2h(float f) {
  union { _Float16 h; u16 u; } v; v.h = (_Float16)f; return v.u;
}
__device__ __forceinline__ float h2f(unsigned int u) {
  union { _Float16 h; u16 u; } v; v.u = (u16)u; return (float)v.h;
}

__global__ void k_zero_i32(int* __restrict__ p, int n) {
  int i = blockIdx.x * blockDim.x + threadIdx.x;
  if (i < n) p[i] = 0;
}

__global__ void k_hist(const int* __restrict__ dst, int* __restrict__ deg, int e) {
  int i = blockIdx.x * blockDim.x + threadIdx.x;
  if (i < e) atomicAdd(&deg[dst[i]], 1);
}

__global__ __launch_bounds__(256) void k_blocksum(const int* __restrict__ deg,
                                                  int* __restrict__ partials) {
  __shared__ int red[256];
  int tid = threadIdx.x;
  int t4 = blockIdx.x * 256 + tid;
  int sum = 0;
  if (t4 < NI4) {
    int4 v = ((const int4*)deg)[t4];
    sum = v.x + v.y + v.z + v.w;
  }
  red[tid] = sum;
  __syncthreads();
  for (int off = 128; off > 0; off >>= 1) {
    if (tid < off) red[tid] += red[tid + off];
    __syncthreads();
  }
  if (tid == 0) partials[blockIdx.x] = red[0];
}

// exclusive scan -> row_ptr; fused: dinv = rsqrt(deg+1), zero deg (cursor reuse)
__global__ __launch_bounds__(256) void k_scan2(int* __restrict__ deg,
                                               const int* __restrict__ partials,
                                               int* __restrict__ row_ptr,
                                               float* __restrict__ dinv) {
  __shared__ int sdata[256];
  __shared__ int sprefix;
  int tid = threadIdx.x, bid = blockIdx.x;
  int t4 = bid * 256 + tid;
  int4 v = make_int4(0, 0, 0, 0);
  if (t4 < NI4) v = ((const int4*)deg)[t4];
  int tsum = v.x + v.y + v.z + v.w;
  sdata[tid] = tsum;
  if (tid == 0) {
    int pre = 0;
    for (int b = 0; b < bid; ++b) pre += partials[b];
    sprefix = pre;
  }
  __syncthreads();
  for (int off = 1; off < 256; off <<= 1) {
    int val = (tid >= off) ? sdata[tid - off] : 0;
    __syncthreads();
    sdata[tid] += val;
    __syncthreads();
  }
  if (t4 < NI4) {
    int run = sdata[tid] - tsum + sprefix;
    int base = t4 * 4;
    float4 dv;
    dv.x = rsqrtf((float)v.x + 1.0f);
    dv.y = rsqrtf((float)v.y + 1.0f);
    dv.z = rsqrtf((float)v.z + 1.0f);
    dv.w = rsqrtf((float)v.w + 1.0f);
    *(float4*)(dinv + base) = dv;
    row_ptr[base + 0] = run; run += v.x;
    row_ptr[base + 1] = run; run += v.y;
    row_ptr[base + 2] = run; run += v.z;
    row_ptr[base + 3] = run; run += v.w;
    if (base + 4 == NNODES) row_ptr[NNODES] = run;
    ((int4*)deg)[t4] = make_int4(0, 0, 0, 0);
  }
}

__global__ void k_fill(const int* __restrict__ src, const int* __restrict__ dst,
                       const float* __restrict__ dinv, const int* __restrict__ row_ptr,
                       int* __restrict__ cursor, int* __restrict__ csr_src,
                       float* __restrict__ csr_nrm, int e) {
  int i = blockIdx.x * blockDim.x + threadIdx.x;
  if (i < e) {
    int d = dst[i], s = src[i];
    int pos = row_ptr[d] + atomicAdd(&cursor[d], 1);
    csr_src[pos] = s;
    csr_nrm[pos] = dinv[s] * dinv[d];
  }
}

// Merged prep: x f32->f16 (ranges [0, x4)) + W hi/lo split ([0, wtot)).
// W packed f16 hi/lo, scaled x256, t-slice-major fragment order:
// slice t (32 k): [hi: 16 ct x 64 lanes x 8 = 8192 u16][lo: 8192 u16]
// frag elem: lane L = q*16+m holds B[k=t*32+q*8+j][n=c*16+m] at (c*64+L)*8+j
__global__ void k_prep(const float* __restrict__ x, u16* __restrict__ xh, int total4,
                       const float* __restrict__ W1f, u16* __restrict__ P1,
                       const float* __restrict__ W2f, u16* __restrict__ P2,
                       const float* __restrict__ W3f, u16* __restrict__ P3) {
  int i = blockIdx.x * blockDim.x + threadIdx.x;
  if (i < total4) {
    float4 v = ((const float4*)x)[i];
    ushort4 o;
    o.x = f2h(v.x); o.y = f2h(v.y); o.z = f2h(v.z); o.w = f2h(v.w);
    ((ushort4*)xh)[i] = o;
  }
  const int s1 = DIN * 256, s2 = s1 + DHID * 256, s3 = s2 + DHID * 256;
  if (i < s3) {
    const float* W; u16* P; int li;
    if (i < s1)      { W = W1f; P = P1; li = i; }
    else if (i < s2) { W = W2f; P = P2; li = i - s1; }
    else             { W = W3f; P = P3; li = i - s2; }
    int k = li >> 8, n = li & 255;
    int t = k >> 5, q = (k >> 3) & 3, j = k & 7;
    int c = n >> 4, m = n & 15;
    int f = (c * 64 + q * 16 + m) * 8 + j;
    float w = W[li] * 256.0f;   // scale keeps lo residues f16-normal
    u16 hi = f2h(w);
    u16 lo = f2h(w - h2f(hi));
    P[(size_t)t * 16384 + f] = hi;
    P[(size_t)t * 16384 + 8192 + f] = lo;
  }
}

// Fused layer v5: producer/consumer wave specialization.
// Round-8 proved the gather is service-rate-bound (26% vs 59% occupancy =
// same time) and that phase-A/phase-B epochs are globally phase-locked
// (all blocks gather, barrier, all blocks GEMM -> serial epochs). Fix:
// waves 0-1 gather tile into double-buffered LDS As while waves 2-3 run
// the MFMA GEMM on the previous tile -> miss path and MFMA pipe busy
// SIMULTANEOUSLY (m114: disjoint pipes co-schedule, time = max not sum).
// Each block handles exactly 2 tiles: bid and bid+GRID (uniform schedule):
//   produce(t0,b0); sync; produce(t1,b1) || consume(t0,b0); sync; consume(t1,b1)
// B fragments read direct from global (fragment-ordered, L2-resident).
// EPI 0: relu + f16 store (all rows). EPI 1: f32 store, rows < NNODES.
template<int K, int EPI>
__global__ __launch_bounds__(256, 3) void k_fused(const u16* __restrict__ hf,
                                                  const float* __restrict__ dinv,
                                                  const int* __restrict__ row_ptr,
                                                  const int* __restrict__ csr_src,
                                                  const float* __restrict__ csr_nrm,
                                                  const u16* __restrict__ Bpk,
                                                  const float* __restrict__ bias,
                                                  u16* __restrict__ hf16,
                                                  float* __restrict__ outf) {
  __shared__ __align__(16) u16 As[2][32 * K];  // 2x8 KB (K=128) / 2x16 KB (K=256)

  const int lane = threadIdx.x & 63;
  const int wave = threadIdx.x >> 6;

  // ---- producer: 2 waves (128 lanes) aggregate 32 rows into As[buf] ----
  auto produce = [&](int t, int buf) {
    constexpr int GL = K / 8;       // lanes per row (16 B/lane, full row)
    constexpr int NGRP = 128 / GL;  // row groups across 2 waves (4 or 8)
    constexpr int RPG = 32 / NGRP;  // rows per group (8 or 4)
    const int pid = threadIdx.x;    // 0..127
    const int gg = pid / GL;
    const int sub = pid % GL;
    const int coff = sub * 8;       // u16 col
    const int nbase = t * 32;

    for (int k = 0; k < RPG; ++k) {
      const int row = gg + k * NGRP;
      const int node = nbase + row;
      float acc[8];
      if (node < NNODES) {
        float di = dinv[node];
        float s2 = di * di;
        {
          half8 v = *(const half8*)(hf + (size_t)node * K + coff);
#pragma unroll
          for (int j = 0; j < 8; ++j) acc[j] = s2 * (float)v[j];
        }
        const int p0 = row_ptr[node];
        const int p1 = row_ptr[node + 1];
        for (int e = p0; e < p1; e += 4) {
          int idx[4]; float w[4];
#pragma unroll
          for (int q = 0; q < 4; ++q) {
            int ii = (e + q < p1) ? e + q : p1 - 1;
            idx[q] = csr_src[ii];
            w[q] = (e + q < p1) ? csr_nrm[ii] : 0.0f;
          }
          half8 v[4];
#pragma unroll
          for (int q = 0; q < 4; ++q)
            v[q] = *(const half8*)(hf + (size_t)idx[q] * K + coff);
#pragma unroll
          for (int q = 0; q < 4; ++q)
#pragma unroll
            for (int j = 0; j < 8; ++j)
              acc[j] = fmaf(w[q], (float)v[q][j], acc[j]);
        }
      } else {
#pragma unroll
        for (int j = 0; j < 8; ++j) acc[j] = 0.0f;
      }
      const int wc = coff ^ ((row & 7) << 3);
      uint4 o;
      o.x = (unsigned)f2h(acc[0]) | ((unsigned)f2h(acc[1]) << 16);
      o.y = (unsigned)f2h(acc[2]) | ((unsigned)f2h(acc[3]) << 16);
      o.z = (unsigned)f2h(acc[4]) | ((unsigned)f2h(acc[5]) << 16);
      o.w = (unsigned)f2h(acc[6]) | ((unsigned)f2h(acc[7]) << 16);
      *(uint4*)&As[buf][row * K + wc] = o;
    }
  };

  // ---- consumer: 2 waves, each 16 rows x 256 cols from As[buf] ----
  auto consume = [&](int t, int buf) {
    const int rw = wave - 2;                 // 0 or 1
    const int m0 = t * 32 + rw * 16;
    const int lr = rw * 16 + (lane & 15);
    const int acoff = (lane >> 4) * 8;

    f32x4 acc0[16];
#pragma unroll
    for (int c = 0; c < 16; ++c) acc0[c] = {0.f, 0.f, 0.f, 0.f};

    for (int tt = 0; tt < K / 32; ++tt) {
      const int ac = acoff + tt * 32;
      half8 a0 = *(const half8*)&As[buf][lr * K + (ac ^ ((lr & 7) << 3))];
      const u16* bt = Bpk + (size_t)tt * 16384 + (size_t)lane * 8;
#pragma unroll
      for (int c = 0; c < 16; ++c) {
        const u16* fb = bt + c * 512;
        half8 bh = *(const half8*)fb;
        half8 bl = *(const half8*)(fb + 8192);
        acc0[c] = __builtin_amdgcn_mfma_f32_16x16x32_f16(a0, bh, acc0[c], 0, 0, 0);
        acc0[c] = __builtin_amdgcn_mfma_f32_16x16x32_f16(a0, bl, acc0[c], 0, 0, 0);
      }
    }

    const int cbase = lane & 15;
    const int r0 = m0 + ((lane >> 4) * 4);
    const float sc = 1.0f / 256.0f;
#pragma unroll
    for (int c = 0; c < 16; ++c) {
      int col = c * 16 + cbase;
      float bv = bias[col];
#pragma unroll
      for (int r = 0; r < 4; ++r) {
        float v0 = fmaf(acc0[c][r], sc, bv);
        if (EPI == 0) {
          v0 = fmaxf(v0, 0.f);
          hf16[(size_t)(r0 + r) * 256 + col] = f2h(v0);
        } else {
          if (r0 + r < NNODES) outf[(size_t)(r0 + r) * 256 + col] = v0;
        }
      }
    }
  };

  const int t0 = blockIdx.x;
  const int t1 = blockIdx.x + GRID;

  if (wave < 2) produce(t0, 0);
  __syncthreads();
  if (wave < 2) produce(t1, 1);
  else          consume(t0, 0);
  __syncthreads();
  if (wave >= 2) consume(t1, 1);
}

extern "C" void kernel_launch(void* const* d_in, const int* in_sizes, int n_in,
                              void* d_out, int out_size, void* d_ws, size_t ws_size,
                              hipStream_t stream) {
  const float* x  = (const float*)d_in[0];
  const int*   ei = (const int*)d_in[1];
  const float* W1 = (const float*)d_in[2];
  const float* b1 = (const float*)d_in[3];
  const float* W2 = (const float*)d_in[4];
  const float* b2 = (const float*)d_in[5];
  const float* W3 = (const float*)d_in[6];
  const float* b3 = (const float*)d_in[7];
  float* out = (float*)d_out;
  (void)in_sizes; (void)n_in; (void)out_size; (void)ws_size;

  char* ws = (char*)d_ws;
  size_t off = 0;
  auto alloc = [&](size_t bytes) -> void* {
    void* p = (void*)(ws + off);
    off += (bytes + 255) & ~(size_t)255;
    return p;
  };
  float* dinv    = (float*)alloc((size_t)NNODES * 4);
  int*   deg     = (int*)alloc((size_t)NNODES * 4);
  int*   row_ptr = (int*)alloc((size_t)(NNODES + 1) * 4);
  int*   partials= (int*)alloc((size_t)NSB * 4);
  int*   csr_src = (int*)alloc((size_t)NEDGES * 4);
  float* csr_nrm = (float*)alloc((size_t)NEDGES * 4);
  u16*   xh      = (u16*)alloc((size_t)NNODES * DIN * 2);    // x as f16
  u16*   hbufA   = (u16*)alloc((size_t)MPAD * 256 * 2);      // h1 f16
  u16*   hbufB   = (u16*)alloc((size_t)MPAD * 256 * 2);      // h2 f16
  u16*   W1pk    = (u16*)alloc((size_t)(DIN / 32) * 16384 * 2);
  u16*   W2pk    = (u16*)alloc((size_t)(DHID / 32) * 16384 * 2);
  u16*   W3pk    = (u16*)alloc((size_t)(DHID / 32) * 16384 * 2);

  const int* e_src = ei;
  const int* e_dst = ei + NEDGES;

  const int tb = 256;
  k_zero_i32<<<(NNODES + tb - 1) / tb, tb, 0, stream>>>(deg, NNODES);
  k_hist<<<(NEDGES + tb - 1) / tb, tb, 0, stream>>>(e_dst, deg, NEDGES);
  k_blocksum<<<NSB, 256, 0, stream>>>(deg, partials);
  k_scan2<<<NSB, 256, 0, stream>>>(deg, partials, row_ptr, dinv);
  k_fill<<<(NEDGES + tb - 1) / tb, tb, 0, stream>>>(e_src, e_dst, dinv, row_ptr, deg,
                                                    csr_src, csr_nrm, NEDGES);

  int x4 = NNODES * DIN / 4;
  k_prep<<<(x4 + tb - 1) / tb, tb, 0, stream>>>(x, xh, x4,
                                                W1, W1pk, W2, W2pk, W3, W3pk);

  // layer 1: agg(x)@W1 fused (producer/consumer)
  k_fused<DIN, 0><<<GRID, 256, 0, stream>>>(xh, dinv, row_ptr, csr_src, csr_nrm,
                                            W1pk, b1, hbufA, nullptr);
  // layer 2
  k_fused<DHID, 0><<<GRID, 256, 0, stream>>>(hbufA, dinv, row_ptr, csr_src, csr_nrm,
                                             W2pk, b2, hbufB, nullptr);
  // layer 3
  k_fused<DHID, 1><<<GRID, 256, 0, stream>>>(hbufB, dinv, row_ptr, csr_src, csr_nrm,
                                             W3pk, b3, nullptr, out);
}

// Round 10
// 305.753 us; speedup vs baseline: 1.5436x; 1.5436x over previous
//
#include <hip/hip_runtime.h>

#define NNODES 50000
#define NEDGES 500000
#define DIN 128
#define DHID 256
#define MPAD 50048   // padded row buffer (>= 1563*32 = 50016)
#define NI4 12500
#define NSB 49

typedef unsigned short u16;
typedef __attribute__((ext_vector_type(8))) _Float16 half8;
typedef __attribute__((ext_vector_type(4))) float f32x4;

__device__ __forceinline__ u16 f2h(float f) {
  union { _Float16 h; u16 u; } v; v.h = (_Float16)f; return v.u;
}
__device__ __forceinline__ float h2f(unsigned int u) {
  union { _Float16 h; u16 u; } v; v.u = (u16)u; return (float)v.h;
}

__global__ void k_zero_i32(int* __restrict__ p, int n) {
  int i = blockIdx.x * blockDim.x + threadIdx.x;
  if (i < n) p[i] = 0;
}

__global__ void k_hist(const int* __restrict__ dst, int* __restrict__ deg, int e) {
  int i = blockIdx.x * blockDim.x + threadIdx.x;
  if (i < e) atomicAdd(&deg[dst[i]], 1);
}

__global__ __launch_bounds__(256) void k_blocksum(const int* __restrict__ deg,
                                                  int* __restrict__ partials) {
  __shared__ int red[256];
  int tid = threadIdx.x;
  int t4 = blockIdx.x * 256 + tid;
  int sum = 0;
  if (t4 < NI4) {
    int4 v = ((const int4*)deg)[t4];
    sum = v.x + v.y + v.z + v.w;
  }
  red[tid] = sum;
  __syncthreads();
  for (int off = 128; off > 0; off >>= 1) {
    if (tid < off) red[tid] += red[tid + off];
    __syncthreads();
  }
  if (tid == 0) partials[blockIdx.x] = red[0];
}

// exclusive scan -> row_ptr; fused: dinv = rsqrt(deg+1), zero deg (cursor reuse)
__global__ __launch_bounds__(256) void k_scan2(int* __restrict__ deg,
                                               const int* __restrict__ partials,
                                               int* __restrict__ row_ptr,
                                               float* __restrict__ dinv) {
  __shared__ int sdata[256];
  __shared__ int sprefix;
  int tid = threadIdx.x, bid = blockIdx.x;
  int t4 = bid * 256 + tid;
  int4 v = make_int4(0, 0, 0, 0);
  if (t4 < NI4) v = ((const int4*)deg)[t4];
  int tsum = v.x + v.y + v.z + v.w;
  sdata[tid] = tsum;
  if (tid == 0) {
    int pre = 0;
    for (int b = 0; b < bid; ++b) pre += partials[b];
    sprefix = pre;
  }
  __syncthreads();
  for (int off = 1; off < 256; off <<= 1) {
    int val = (tid >= off) ? sdata[tid - off] : 0;
    __syncthreads();
    sdata[tid] += val;
    __syncthreads();
  }
  if (t4 < NI4) {
    int run = sdata[tid] - tsum + sprefix;
    int base = t4 * 4;
    float4 dv;
    dv.x = rsqrtf((float)v.x + 1.0f);
    dv.y = rsqrtf((float)v.y + 1.0f);
    dv.z = rsqrtf((float)v.z + 1.0f);
    dv.w = rsqrtf((float)v.w + 1.0f);
    *(float4*)(dinv + base) = dv;
    row_ptr[base + 0] = run; run += v.x;
    row_ptr[base + 1] = run; run += v.y;
    row_ptr[base + 2] = run; run += v.z;
    row_ptr[base + 3] = run; run += v.w;
    if (base + 4 == NNODES) row_ptr[NNODES] = run;
    ((int4*)deg)[t4] = make_int4(0, 0, 0, 0);
  }
}

__global__ void k_fill(const int* __restrict__ src, const int* __restrict__ dst,
                       const float* __restrict__ dinv, const int* __restrict__ row_ptr,
                       int* __restrict__ cursor, int* __restrict__ csr_src,
                       float* __restrict__ csr_nrm, int e) {
  int i = blockIdx.x * blockDim.x + threadIdx.x;
  if (i < e) {
    int d = dst[i], s = src[i];
    int pos = row_ptr[d] + atomicAdd(&cursor[d], 1);
    csr_src[pos] = s;
    csr_nrm[pos] = dinv[s] * dinv[d];
  }
}

// Merged prep: x f32->f16 (ranges [0, x4)) + W hi/lo split ([0, wtot)).
// W packed f16 hi/lo, scaled x256, t-slice-major fragment order:
// slice t (32 k): [hi: 16 ct x 64 lanes x 8 = 8192 u16][lo: 8192 u16]
// frag elem: lane L = q*16+m holds B[k=t*32+q*8+j][n=c*16+m] at (c*64+L)*8+j
__global__ void k_prep(const float* __restrict__ x, u16* __restrict__ xh, int total4,
                       const float* __restrict__ W1f, u16* __restrict__ P1,
                       const float* __restrict__ W2f, u16* __restrict__ P2,
                       const float* __restrict__ W3f, u16* __restrict__ P3) {
  int i = blockIdx.x * blockDim.x + threadIdx.x;
  if (i < total4) {
    float4 v = ((const float4*)x)[i];
    ushort4 o;
    o.x = f2h(v.x); o.y = f2h(v.y); o.z = f2h(v.z); o.w = f2h(v.w);
    ((ushort4*)xh)[i] = o;
  }
  const int s1 = DIN * 256, s2 = s1 + DHID * 256, s3 = s2 + DHID * 256;
  if (i < s3) {
    const float* W; u16* P; int li;
    if (i < s1)      { W = W1f; P = P1; li = i; }
    else if (i < s2) { W = W2f; P = P2; li = i - s1; }
    else             { W = W3f; P = P3; li = i - s2; }
    int k = li >> 8, n = li & 255;
    int t = k >> 5, q = (k >> 3) & 3, j = k & 7;
    int c = n >> 4, m = n & 15;
    int f = (c * 64 + q * 16 + m) * 8 + j;
    float w = W[li] * 256.0f;   // scale keeps lo residues f16-normal
    u16 hi = f2h(w);
    u16 lo = f2h(w - h2f(hi));
    P[(size_t)t * 16384 + f] = hi;
    P[(size_t)t * 16384 + 8192 + f] = lo;
  }
}

// Fused layer v6 (r8 base + 2 fixes):
// 1. DYNAMIC row assignment in produce: LDS atomic counter; each GL-lane
//    group pulls the next row when done (r8's static 4-row groups made the
//    barrier wait for the max group: Poisson-degree straggler ~ +30% on the
//    gather epoch; r6 vs r8 identical 76us despite 3x occupancy / 2x B
//    traffic fingered the straggler, not bandwidth, as the extra cost).
// 2. Dedup-B consumer mapping: wave w owns col-frags 4w..4w+3 for BOTH
//    16-row A-frags (acc[2][4]) -> each B frag read once per tile (was 2x).
// All 4 waves gather (r9 proved gather scales ~linearly to ~19-24 waves/CU
// at ~0.16 TB/s/wave; specialization starves it). 32-row tiles, 16 KB LDS.
// EPI 0: relu + f16 store (all rows). EPI 1: f32 store, rows < NNODES.
template<int K, int EPI>
__global__ __launch_bounds__(256, 6) void k_fused(const u16* __restrict__ hf,
                                                  const float* __restrict__ dinv,
                                                  const int* __restrict__ row_ptr,
                                                  const int* __restrict__ csr_src,
                                                  const float* __restrict__ csr_nrm,
                                                  const u16* __restrict__ Bpk,
                                                  const float* __restrict__ bias,
                                                  u16* __restrict__ hf16,
                                                  float* __restrict__ outf) {
  __shared__ __align__(16) u16 As[32 * K];  // 8 KB (K=128) / 16 KB (K=256)
  __shared__ int nextrow;

  const int lane = threadIdx.x & 63;
  const int wave = threadIdx.x >> 6;

  if (threadIdx.x == 0) nextrow = 0;
  __syncthreads();

  // ------- phase A: aggregate 32 rows into As (dynamic row-stealing) -------
  {
    constexpr int GL = K / 8;            // lanes per row (16 B/lane, full row)
    const int sub = threadIdx.x % GL;
    const int gbase = lane - (lane % GL); // group's base lane within wave
    const int coff = sub * 8;            // u16 col
    const int nbase = blockIdx.x * 32;

    for (;;) {
      int row;
      if (sub == 0) row = atomicAdd(&nextrow, 1);
      row = __shfl(row, gbase);
      if (row >= 32) break;
      const int node = nbase + row;
      float acc[8];
      if (node < NNODES) {
        float di = dinv[node];
        float s2 = di * di;
        {
          half8 v = *(const half8*)(hf + (size_t)node * K + coff);
#pragma unroll
          for (int j = 0; j < 8; ++j) acc[j] = s2 * (float)v[j];
        }
        const int p0 = row_ptr[node];
        const int p1 = row_ptr[node + 1];
        for (int e = p0; e < p1; e += 4) {
          int idx[4]; float w[4];
#pragma unroll
          for (int q = 0; q < 4; ++q) {
            int ii = (e + q < p1) ? e + q : p1 - 1;
            idx[q] = csr_src[ii];
            w[q] = (e + q < p1) ? csr_nrm[ii] : 0.0f;
          }
          half8 v[4];
#pragma unroll
          for (int q = 0; q < 4; ++q)
            v[q] = *(const half8*)(hf + (size_t)idx[q] * K + coff);
#pragma unroll
          for (int q = 0; q < 4; ++q)
#pragma unroll
            for (int j = 0; j < 8; ++j)
              acc[j] = fmaf(w[q], (float)v[q][j], acc[j]);
        }
      } else {
#pragma unroll
        for (int j = 0; j < 8; ++j) acc[j] = 0.0f;
      }
      const int wc = coff ^ ((row & 7) << 3);
      uint4 o;
      o.x = (unsigned)f2h(acc[0]) | ((unsigned)f2h(acc[1]) << 16);
      o.y = (unsigned)f2h(acc[2]) | ((unsigned)f2h(acc[3]) << 16);
      o.z = (unsigned)f2h(acc[4]) | ((unsigned)f2h(acc[5]) << 16);
      o.w = (unsigned)f2h(acc[6]) | ((unsigned)f2h(acc[7]) << 16);
      *(uint4*)&As[row * K + wc] = o;
    }
  }

  __syncthreads();   // As complete; no further barriers needed

  // ------- phase B: barrier-free GEMM, A from LDS, B from global -------
  // Wave w: col-frags 4w..4w+3, both 16-row A-frags. B read once per tile.
  const int cb = wave * 4;
  const int lr0 = lane & 15;
  const int lr1 = 16 + lr0;
  const int acoff = (lane >> 4) * 8;

  f32x4 acc0[4], acc1[4];
#pragma unroll
  for (int c = 0; c < 4; ++c) {
    acc0[c] = {0.f, 0.f, 0.f, 0.f};
    acc1[c] = {0.f, 0.f, 0.f, 0.f};
  }

  for (int t = 0; t < K / 32; ++t) {
    const int ac = acoff + t * 32;
    half8 a0 = *(const half8*)&As[lr0 * K + (ac ^ ((lr0 & 7) << 3))];
    half8 a1 = *(const half8*)&As[lr1 * K + (ac ^ ((lr1 & 7) << 3))];
    const u16* bt = Bpk + (size_t)t * 16384 + ((size_t)cb * 64 + lane) * 8;
#pragma unroll
    for (int c = 0; c < 4; ++c) {
      const u16* fb = bt + c * 512;
      half8 bh = *(const half8*)fb;
      half8 bl = *(const half8*)(fb + 8192);
      acc0[c] = __builtin_amdgcn_mfma_f32_16x16x32_f16(a0, bh, acc0[c], 0, 0, 0);
      acc0[c] = __builtin_amdgcn_mfma_f32_16x16x32_f16(a0, bl, acc0[c], 0, 0, 0);
      acc1[c] = __builtin_amdgcn_mfma_f32_16x16x32_f16(a1, bh, acc1[c], 0, 0, 0);
      acc1[c] = __builtin_amdgcn_mfma_f32_16x16x32_f16(a1, bl, acc1[c], 0, 0, 0);
    }
  }

  const int cbase = lane & 15;
  const int r0 = blockIdx.x * 32 + ((lane >> 4) * 4);
  const float sc = 1.0f / 256.0f;
#pragma unroll
  for (int c = 0; c < 4; ++c) {
    int col = (cb + c) * 16 + cbase;
    float bv = bias[col];
#pragma unroll
    for (int r = 0; r < 4; ++r) {
      float v0 = fmaf(acc0[c][r], sc, bv);
      float v1 = fmaf(acc1[c][r], sc, bv);
      if (EPI == 0) {
        v0 = fmaxf(v0, 0.f);
        v1 = fmaxf(v1, 0.f);
        hf16[(size_t)(r0 + r) * 256 + col] = f2h(v0);
        hf16[(size_t)(r0 + 16 + r) * 256 + col] = f2h(v1);
      } else {
        if (r0 + r < NNODES) outf[(size_t)(r0 + r) * 256 + col] = v0;
        if (r0 + 16 + r < NNODES) outf[(size_t)(r0 + 16 + r) * 256 + col] = v1;
      }
    }
  }
}

extern "C" void kernel_launch(void* const* d_in, const int* in_sizes, int n_in,
                              void* d_out, int out_size, void* d_ws, size_t ws_size,
                              hipStream_t stream) {
  const float* x  = (const float*)d_in[0];
  const int*   ei = (const int*)d_in[1];
  const float* W1 = (const float*)d_in[2];
  const float* b1 = (const float*)d_in[3];
  const float* W2 = (const float*)d_in[4];
  const float* b2 = (const float*)d_in[5];
  const float* W3 = (const float*)d_in[6];
  const float* b3 = (const float*)d_in[7];
  float* out = (float*)d_out;
  (void)in_sizes; (void)n_in; (void)out_size; (void)ws_size;

  char* ws = (char*)d_ws;
  size_t off = 0;
  auto alloc = [&](size_t bytes) -> void* {
    void* p = (void*)(ws + off);
    off += (bytes + 255) & ~(size_t)255;
    return p;
  };
  float* dinv    = (float*)alloc((size_t)NNODES * 4);
  int*   deg     = (int*)alloc((size_t)NNODES * 4);
  int*   row_ptr = (int*)alloc((size_t)(NNODES + 1) * 4);
  int*   partials= (int*)alloc((size_t)NSB * 4);
  int*   csr_src = (int*)alloc((size_t)NEDGES * 4);
  float* csr_nrm = (float*)alloc((size_t)NEDGES * 4);
  u16*   xh      = (u16*)alloc((size_t)NNODES * DIN * 2);    // x as f16
  u16*   hbufA   = (u16*)alloc((size_t)MPAD * 256 * 2);      // h1 f16
  u16*   hbufB   = (u16*)alloc((size_t)MPAD * 256 * 2);      // h2 f16
  u16*   W1pk    = (u16*)alloc((size_t)(DIN / 32) * 16384 * 2);
  u16*   W2pk    = (u16*)alloc((size_t)(DHID / 32) * 16384 * 2);
  u16*   W3pk    = (u16*)alloc((size_t)(DHID / 32) * 16384 * 2);

  const int* e_src = ei;
  const int* e_dst = ei + NEDGES;

  const int tb = 256;
  k_zero_i32<<<(NNODES + tb - 1) / tb, tb, 0, stream>>>(deg, NNODES);
  k_hist<<<(NEDGES + tb - 1) / tb, tb, 0, stream>>>(e_dst, deg, NEDGES);
  k_blocksum<<<NSB, 256, 0, stream>>>(deg, partials);
  k_scan2<<<NSB, 256, 0, stream>>>(deg, partials, row_ptr, dinv);
  k_fill<<<(NEDGES + tb - 1) / tb, tb, 0, stream>>>(e_src, e_dst, dinv, row_ptr, deg,
                                                    csr_src, csr_nrm, NEDGES);

  int x4 = NNODES * DIN / 4;
  k_prep<<<(x4 + tb - 1) / tb, tb, 0, stream>>>(x, xh, x4,
                                                W1, W1pk, W2, W2pk, W3, W3pk);

  const int gblocks = (NNODES + 31) / 32;  // 1563

  // layer 1: agg(x)@W1 fused
  k_fused<DIN, 0><<<gblocks, 256, 0, stream>>>(xh, dinv, row_ptr, csr_src, csr_nrm,
                                               W1pk, b1, hbufA, nullptr);
  // layer 2
  k_fused<DHID, 0><<<gblocks, 256, 0, stream>>>(hbufA, dinv, row_ptr, csr_src, csr_nrm,
                                                W2pk, b2, hbufB, nullptr);
  // layer 3
  k_fused<DHID, 1><<<gblocks, 256, 0, stream>>>(hbufB, dinv, row_ptr, csr_src, csr_nrm,
                                                W3pk, b3, nullptr, out);
}